// Round 4
// baseline (200.978 us; speedup 1.0000x reference)
//
#include <hip/hip_runtime.h>
#include <cstdint>
#include <cstddef>

#define N_CLS 80
#define TOPK 1000
#define POOL_N 2048
#define MCAP 512
#define WRDS 8
#define DTB 128

// ---------------- K1: decode + score + per-class binning -------------------
// Per-thread arithmetic identical to rounds 1-3 (bit-exact, absmax 0.0).
__global__ __launch_bounds__(DTB) void decode_kernel(
    const float* __restrict__ reg, const float* __restrict__ obj,
    const float* __restrict__ cls, const float* __restrict__ grid,
    const float* __restrict__ anch, const float* __restrict__ strd,
    float* __restrict__ boxes, uint2* __restrict__ scs,
    int* __restrict__ gcnt, uint2* __restrict__ gpool, int N) {
  __shared__ __align__(16) float tile[DTB * 84];
  const int tb = blockIdx.x * DTB;
  const int na = min(DTB, N - tb);
  const int nf4 = na * 20;
  const float4* cg = (const float4*)cls + (size_t)tb * 20;
  float4* tf4 = (float4*)tile;
  for (int j = threadIdx.x; j < nf4; j += DTB) {
    int a = j / 20;
    int p = j - a * 20;
    tf4[a * 21 + p] = cg[j];
  }
  __syncthreads();

  const int t = threadIdx.x;
  const int i = tb + t;
  if (i >= N) return;

  const float4 r = ((const float4*)reg)[i];
  const float2 g = ((const float2*)grid)[i];
  const float2 aw = ((const float2*)anch)[i];
  const float st = strd[i];

  float cx = (1.0f / (1.0f + expf(-r.x)) + g.x) * st;
  float cy = (1.0f / (1.0f + expf(-r.y)) + g.y) * st;
  float w = expf(r.z) * aw.x;
  float h = expf(r.w) * aw.y;
  float b0 = fminf(fmaxf((cx - 0.5f * w) / 640.0f, 0.0f), 1.0f);
  float b1 = fminf(fmaxf((cy - 0.5f * h) / 640.0f, 0.0f), 1.0f);
  float b2 = fminf(fmaxf((cx + 0.5f * w) / 640.0f, 0.0f), 1.0f);
  float b3 = fminf(fmaxf((cy + 0.5f * h) / 640.0f, 0.0f), 1.0f);
  float4 bo; bo.x = b0; bo.y = b1; bo.z = b2; bo.w = b3;
  ((float4*)boxes)[i] = bo;

  float x[N_CLS];
#pragma unroll
  for (int q = 0; q < N_CLS / 4; ++q) {
    float4 v = tf4[t * 21 + q];
    x[4 * q + 0] = v.x; x[4 * q + 1] = v.y;
    x[4 * q + 2] = v.z; x[4 * q + 3] = v.w;
  }
  float mx = x[0];
#pragma unroll
  for (int c = 1; c < N_CLS; ++c) mx = fmaxf(mx, x[c]);
  float s = 0.0f;
#pragma unroll
  for (int c = 0; c < N_CLS; ++c) { float e = expf(x[c] - mx); x[c] = e; s += e; }
  float sig = 1.0f / (1.0f + expf(-obj[i]));
  float best = -1.0f; int bc = 0;
#pragma unroll
  for (int c = 0; c < N_CLS; ++c) {
    float q = sig * (x[c] / s);
    if (q > best) { best = q; bc = c; }
  }
  scs[i] = make_uint2(__float_as_uint(best), (unsigned)bc);
  if (best >= 0.001f) {
    int p = atomicAdd(&gcnt[bc], 1);
    if (p < POOL_N) gpool[bc * POOL_N + p] = make_uint2(__float_as_uint(best), (unsigned)i);
  }
}

// ---------------- K2: per-class rank sort + fillers + gather ---------------
__global__ __launch_bounds__(256) void sort_kernel(
    const float* __restrict__ boxes, const uint2* __restrict__ scs,
    const int* __restrict__ gcnt, const uint2* __restrict__ gpool,
    float* __restrict__ sbox, float* __restrict__ svals_g,
    int* __restrict__ mArr, int N) {
  const int c = blockIdx.x;
  const int tid = threadIdx.x;
  __shared__ uint2 pool[POOL_N];
  __shared__ float svals[TOPK];
  __shared__ int sidx[TOPK];
  __shared__ int wsum[5];

  const int cnt = min(gcnt[c], POOL_N);
  const int m = min(cnt, TOPK);
  for (int p = tid; p < cnt; p += 256) pool[p] = gpool[c * POOL_N + p];
  __syncthreads();

  // rank sort: value desc, ties -> index asc (== jax.lax.top_k order);
  // total order => independent of nondeterministic bin order.
  for (int e = tid; e < cnt; e += 256) {
    uint2 me = pool[e];
    float v = __uint_as_float(me.x);
    int idx = (int)me.y;
    int r = 0;
#pragma unroll 4
    for (int k = 0; k < cnt; ++k) {
      uint2 q = pool[k];
      float vk = __uint_as_float(q.x);
      r += (int)((vk > v) || (vk == v && (int)q.y < idx));
    }
    if (r < TOPK) { svals[r] = v; sidx[r] = idx; }
  }
  __syncthreads();

  // fillers: lowest-index non-matching anchors, ascending
  const int M = TOPK - m;
  if (M > 0) {
    int carry = 0;
    for (int base = 0; base < N && carry < M; base += 256) {
      int i = base + tid;
      bool f = false;
      if (i < N) {
        uint2 sc = scs[i];
        f = !((int)sc.y == c && __uint_as_float(sc.x) >= 0.001f);
      }
      unsigned long long mk = __ballot(f ? 1 : 0);
      int lane = tid & 63, wv = tid >> 6;
      int pre = __popcll(mk & ((1ULL << lane) - 1ULL));
      if (lane == 0) wsum[wv] = __popcll(mk);
      __syncthreads();
      if (tid == 0) {
        int acc = 0;
        for (int wq = 0; wq < 4; ++wq) { int t2 = wsum[wq]; wsum[wq] = acc; acc += t2; }
        wsum[4] = acc;
      }
      __syncthreads();
      int pos = carry + wsum[wv] + pre;
      if (f && pos < M) sidx[m + pos] = i;
      carry += wsum[4];
      __syncthreads();
    }
  }
  __syncthreads();

  const float4* bf4 = (const float4*)boxes;
  float4* sb4 = (float4*)sbox;
  for (int t = tid; t < TOPK; t += 256) {
    sb4[c * TOPK + t] = bf4[sidx[t]];
    svals_g[c * TOPK + t] = (t < m) ? svals[t] : -1.0f;
  }
  if (tid == 0) mArr[c] = m;
}

// ---------------- K3: bitmask build, 8 row-chunks x 80 classes -------------
__global__ __launch_bounds__(256) void build_kernel(
    const float* __restrict__ sbox, const int* __restrict__ mArr,
    unsigned long long* __restrict__ bitmat_g) {
  const int c = blockIdx.x >> 3;
  const int chunk = blockIdx.x & 7;
  const int m = mArr[c];
  if (m > MCAP) return;               // fallback path handled in out_kernel
  const int r0 = chunk << 6;
  if (r0 >= m) return;
  __shared__ __align__(16) float4 bx[MCAP];
  const float4* sb4 = (const float4*)sbox + (size_t)c * TOPK;
  for (int t = threadIdx.x; t < m; t += 256) bx[t] = sb4[t];
  __syncthreads();
  const int nr = min(64, m - r0);
  const int W = (m + 63) >> 6;
  const int tasks = nr * W;
  unsigned long long* bm = bitmat_g + (size_t)c * MCAP * WRDS;
  for (int q = threadIdx.x; q < tasks; q += 256) {
    int w = q / nr;                   // adjacent threads -> adjacent rows
    int row = r0 + (q - w * nr);      // => bx[j] broadcast across the wave
    unsigned long long bits = 0ULL;
    if (w >= (row >> 6)) {
      float4 rb = bx[row];
      float ai = (rb.z - rb.x) * (rb.w - rb.y);
      int j0 = w << 6, jend = min(j0 + 64, m);
      for (int j = max(j0, row + 1); j < jend; ++j) {
        float4 jb = bx[j];
        float aj = (jb.z - jb.x) * (jb.w - jb.y);
        float xx1 = fmaxf(rb.x, jb.x), yy1 = fmaxf(rb.y, jb.y);
        float xx2 = fminf(rb.z, jb.z), yy2 = fminf(rb.w, jb.w);
        float ww = fmaxf(1e-28f, xx2 - xx1), hh = fmaxf(1e-28f, yy2 - yy1);
        float inter = ww * hh;
        float iou = inter / (ai + aj - inter + 1e-14f);
        if (iou > 0.6f) bits |= (1ULL << (j - j0));
      }
    }
    bm[(size_t)row * WRDS + w] = bits;  // lower-triangle words written as 0
  }
}

__device__ __forceinline__ unsigned long long kinit(int w, int m) {
  int lo = w << 6;
  return (m <= lo) ? 0ULL : ((m - lo >= 64) ? ~0ULL : ((1ULL << (m - lo)) - 1ULL));
}

// ---------------- K4: greedy scan (prefetch-4 pipeline) + outputs ----------
__global__ __launch_bounds__(256) void out_kernel(
    const float* __restrict__ sbox, const float* __restrict__ svals_g,
    const int* __restrict__ mArr,
    const unsigned long long* __restrict__ bitmat_g,
    float* __restrict__ out) {
  const int c = blockIdx.x;
  const int tid = threadIdx.x;
  const int m = mArr[c];
  __shared__ __align__(16) unsigned long long ldsB[MCAP * WRDS];  // 32 KB
  __shared__ unsigned long long kpw[WRDS];
  __shared__ unsigned char kp[TOPK];
  const float4* sb4 = (const float4*)sbox + (size_t)c * TOPK;

  if (m <= MCAP) {
    const unsigned long long* bg = bitmat_g + (size_t)c * MCAP * WRDS;
    const int nw = m * WRDS;
    for (int u = tid; u < nw; u += 256) ldsB[u] = bg[u];
    __syncthreads();
    if (tid < 64) {
      unsigned long long km0 = kinit(0, m), km1 = kinit(1, m),
                         km2 = kinit(2, m), km3 = kinit(3, m),
                         km4 = kinit(4, m), km5 = kinit(5, m),
                         km6 = kinit(6, m), km7 = kinit(7, m);
      if (m > 0) {
        const ulonglong2* rp = (const ulonglong2*)ldsB;
        ulonglong2 A0, A1, A2, A3, B0, B1, B2, B3;
        ulonglong2 C0, C1, C2, C3, D0, D1, D2, D3;
        { const ulonglong2* p = rp;                              A0=p[0];A1=p[1];A2=p[2];A3=p[3]; }
        { const ulonglong2* p = rp + (size_t)min(1, m - 1) * 4;  B0=p[0];B1=p[1];B2=p[2];B3=p[3]; }
        { const ulonglong2* p = rp + (size_t)min(2, m - 1) * 4;  C0=p[0];C1=p[1];C2=p[2];C3=p[3]; }
        { const ulonglong2* p = rp + (size_t)min(3, m - 1) * 4;  D0=p[0];D1=p[1];D2=p[2];D3=p[3]; }
#define APPLY8(T0, T1, T2, T3)                                          \
        { km0 &= ~T0.x; km1 &= ~T0.y; km2 &= ~T1.x; km3 &= ~T1.y;       \
          km4 &= ~T2.x; km5 &= ~T2.y; km6 &= ~T3.x; km7 &= ~T3.y; }
#define STAGE(BF0, BF1, BF2, BF3, KMW, I)                               \
        { int i_ = (I);                                                 \
          if (i_ < m) {                                                 \
            ulonglong2 t0_ = BF0, t1_ = BF1, t2_ = BF2, t3_ = BF3;      \
            int nx_ = i_ + 4; if (nx_ >= m) nx_ = m - 1;                \
            const ulonglong2* np_ = rp + (size_t)nx_ * 4;               \
            BF0 = np_[0]; BF1 = np_[1]; BF2 = np_[2]; BF3 = np_[3];     \
            if ((KMW >> (i_ & 63)) & 1ULL) APPLY8(t0_, t1_, t2_, t3_)   \
          } }
#define WSEC(WI, KMW)                                                   \
        if ((WI << 6) < m) {                                            \
          for (int b = 0; b < 64; b += 4) {                             \
            int base = (WI << 6) + b;                                   \
            if (base >= m) break;                                       \
            STAGE(A0, A1, A2, A3, KMW, base)                            \
            STAGE(B0, B1, B2, B3, KMW, base + 1)                        \
            STAGE(C0, C1, C2, C3, KMW, base + 2)                        \
            STAGE(D0, D1, D2, D3, KMW, base + 3)                        \
          } }
        WSEC(0, km0) WSEC(1, km1) WSEC(2, km2) WSEC(3, km3)
        WSEC(4, km4) WSEC(5, km5) WSEC(6, km6) WSEC(7, km7)
#undef WSEC
#undef STAGE
#undef APPLY8
      }
      if (tid == 0) {
        kpw[0] = km0; kpw[1] = km1; kpw[2] = km2; kpw[3] = km3;
        kpw[4] = km4; kpw[5] = km5; kpw[6] = km6; kpw[7] = km7;
      }
    }
    __syncthreads();
  } else {
    // fallback (m > MCAP; not hit on this data): serial barrier loop
    float4* bb = (float4*)ldsB;                   // m <= TOPK -> 16 KB
    for (int t = tid; t < m; t += 256) bb[t] = sb4[t];
    for (int t = tid; t < TOPK; t += 256) kp[t] = (t < m) ? 1 : 0;
    __syncthreads();
    for (int i = 0; i < m; ++i) {
      if (kp[i]) {
        float4 rb = bb[i];
        float ai = (rb.z - rb.x) * (rb.w - rb.y);
        for (int j = i + 1 + tid; j < m; j += 256) {
          if (kp[j]) {
            float4 jb = bb[j];
            float aj = (jb.z - jb.x) * (jb.w - jb.y);
            float xx1 = fmaxf(rb.x, jb.x), yy1 = fmaxf(rb.y, jb.y);
            float xx2 = fminf(rb.z, jb.z), yy2 = fminf(rb.w, jb.w);
            float ww = fmaxf(1e-28f, xx2 - xx1), hh = fmaxf(1e-28f, yy2 - yy1);
            float inter = ww * hh;
            float iou = inter / (ai + aj - inter + 1e-14f);
            if (iou > 0.6f) kp[j] = 0;
          }
        }
      }
      __syncthreads();
    }
  }

  // outputs: boxes [80,1000,4], scores*keep [80,1000], keep [80,1000]
  float* outB = out;
  float* outS = out + N_CLS * TOPK * 4;
  float* outK = outS + N_CLS * TOPK;
  const bool pathA = (m <= MCAP);
  for (int t = tid; t < TOPK; t += 256) {
    float k = 0.0f;
    if (t < m)
      k = pathA ? (float)((kpw[t >> 6] >> (t & 63)) & 1ULL) : (float)kp[t];
    float v = svals_g[c * TOPK + t];              // -1.0 for t >= m
    ((float4*)outB)[c * TOPK + t] = sb4[t];
    outS[c * TOPK + t] = v * k;
    outK[c * TOPK + t] = k;
  }
}

extern "C" void kernel_launch(void* const* d_in, const int* in_sizes, int n_in,
                              void* d_out, int out_size, void* d_ws, size_t ws_size,
                              hipStream_t stream) {
  const float* reg  = (const float*)d_in[0];
  const float* obj  = (const float*)d_in[1];
  const float* cls  = (const float*)d_in[2];
  const float* grid = (const float*)d_in[3];
  const float* anch = (const float*)d_in[4];
  const float* strd = (const float*)d_in[5];
  const int N = in_sizes[0] / 4;  // 25200

  char* w8 = (char*)d_ws;
  size_t off = 0;
  float* boxes = (float*)(w8 + off); off += (size_t)N * 16;
  uint2* scs   = (uint2*)(w8 + off); off += (size_t)N * 8;
  int* gcnt    = (int*)(w8 + off);   off += 512;            // 80 ints, padded
  int* mArr    = (int*)(w8 + off);   off += 512;
  uint2* gpool = (uint2*)(w8 + off); off += (size_t)N_CLS * POOL_N * 8;
  float* svals_g = (float*)(w8 + off); off += (size_t)N_CLS * TOPK * 4;
  float* sbox  = (float*)(w8 + off); off += (size_t)N_CLS * TOPK * 16;
  unsigned long long* bitmat_g = (unsigned long long*)(w8 + off);
  float* out = (float*)d_out;

  hipMemsetAsync(gcnt, 0, N_CLS * sizeof(int), stream);
  decode_kernel<<<(N + DTB - 1) / DTB, DTB, 0, stream>>>(
      reg, obj, cls, grid, anch, strd, boxes, scs, gcnt, gpool, N);
  sort_kernel<<<N_CLS, 256, 0, stream>>>(boxes, scs, gcnt, gpool,
                                         sbox, svals_g, mArr, N);
  build_kernel<<<N_CLS * 8, 256, 0, stream>>>(sbox, mArr, bitmat_g);
  out_kernel<<<N_CLS, 256, 0, stream>>>(sbox, svals_g, mArr, bitmat_g, out);
}